// Round 3
// baseline (179.855 us; speedup 1.0000x reference)
//
#include <hip/hip_runtime.h>
#include <hip/hip_bf16.h>
#include <stdint.h>

#define KDIM 4096
#define BM 128
#define BN 128
#define BK 64
#define NT (KDIM / BK)   // 64 K-steps

typedef __attribute__((ext_vector_type(8))) short bf16x8;
typedef __attribute__((ext_vector_type(4))) float f32x4;

__device__ inline unsigned short f2bf_bits(float f) {
  union { __hip_bfloat16 h; unsigned short u; } cv;
  cv.h = __float2bfloat16(f);
  return cv.u;
}

// Replicates: scaled = t / bm * 6; q = sign * nearest_palette(|scaled|) (ties -> lower);
// dq = q * (bm/6), rounded to bf16. Division kept exact (fp32 div) so palette
// boundary decisions bit-match the reference.
__device__ inline unsigned short qdq(float t, float bm, float scale) {
  float s = t / bm;
  s = s * 6.0f;
  float a = fabsf(s);
  float v;
  if (a <= 0.25f)      v = 0.0f;
  else if (a <= 0.75f) v = 0.5f;
  else if (a <= 1.25f) v = 1.0f;
  else if (a <= 1.75f) v = 1.5f;
  else if (a <= 2.5f)  v = 2.0f;
  else if (a <= 3.5f)  v = 3.0f;
  else if (a <= 5.0f)  v = 4.0f;
  else                 v = 6.0f;
  float q = copysignf(v, s);
  return f2bf_bits(q * scale);
}

// Fused quant+dequant for both tensors. One 8-lane subgroup = one 32-elem block.
__global__ void nvfp4_quant_dq2(const float* __restrict__ x, unsigned short* __restrict__ xq,
                                int nsub_x,
                                const float* __restrict__ w, unsigned short* __restrict__ wq,
                                int nsub_total) {
  int gid = blockIdx.x * blockDim.x + threadIdx.x;
  int sub = gid >> 3;
  if (sub >= nsub_total) return;
  const float* in;
  unsigned short* out;
  if (sub < nsub_x) { in = x; out = xq; }
  else { in = w; out = wq; sub -= nsub_x; }
  int l8 = gid & 7;
  long base = (long)sub * 32 + (long)l8 * 4;
  const float4 v = *(const float4*)(in + base);
  float amax = fmaxf(fmaxf(fabsf(v.x), fabsf(v.y)), fmaxf(fabsf(v.z), fabsf(v.w)));
  amax = fmaxf(amax, __shfl_xor(amax, 1));
  amax = fmaxf(amax, __shfl_xor(amax, 2));
  amax = fmaxf(amax, __shfl_xor(amax, 4));
  float bm = fmaxf(amax, 1e-12f);   // jnp.clip(max, 1e-12)
  float scale = bm / 6.0f;
  ushort4 o;
  o.x = qdq(v.x, bm, scale);
  o.y = qdq(v.y, bm, scale);
  o.z = qdq(v.z, bm, scale);
  o.w = qdq(v.w, bm, scale);
  *(ushort4*)(out + base) = o;
}

// C[M,N] = A[M,K](bf16) * B[N,K]^T(bf16).
// 128x128 tile, BK=64, 4 waves (2x2), each wave 64x64 via 4x4 grid of 16x16x32 MFMA.
// Double-buffered (64 KB LDS -> 2 blocks/CU for TLP). Counted s_waitcnt vmcnt(8),
// raw s_barriers (no __syncthreads -> no forced vmcnt(0) drain). LDS chunk-XOR
// swizzle applied on the GLOBAL source (global_load_lds writes linearly) + on the
// ds_read address. Grid = 256 blocks; XCD-chunked block swizzle.
__global__ __launch_bounds__(256, 2) void gemm_bf16_bt(
    const unsigned short* __restrict__ A,  // [M, K]
    const unsigned short* __restrict__ B,  // [N, K]
    float* __restrict__ C, int M, int N) {
  __shared__ unsigned short As[2][BM * BK];   // 2 x 16 KB
  __shared__ unsigned short Bs[2][BN * BK];   // 2 x 16 KB  (64 KB total)

  const int tid = threadIdx.x;
  const int wave = tid >> 6;
  const int lane = tid & 63;
  const int wm = wave >> 1;       // 0..1  (64-row half)
  const int wn = wave & 1;        // 0..1  (64-col half)
  const int quad = lane >> 4;     // 0..3
  const int r16 = lane & 15;      // 0..15

  const int nbx = N / BN;
  const int nby = M / BM;
  int bx, by;
  {
    int bid = blockIdx.x;
    if (nbx == 32 && nby == 8) {
      // XCD-chunked swizzle: XCD x gets bx in [4x, 4x+4) x all 8 by.
      int xcd = bid & 7;
      int c = bid >> 3;
      bx = xcd * 4 + (c & 3);
      by = c >> 2;
    } else {
      bx = bid % nbx;
      by = bid / nbx;
    }
  }
  const int bm0 = by * BM;
  const int bn0 = bx * BN;

  // ---- staging map: tile = 128 rows x 8 chunks of 16B; 1024 slots; 4 per thread.
  // LDS slot (row, ch) receives GLOBAL chunk (ch ^ (row&7))  [inverse-swizzled source,
  // linear LDS dest -> reads with the same XOR get global chunk c conflict-free].
  const unsigned short* gA[4];
  const unsigned short* gB[4];
  int offS[4];
#pragma unroll
  for (int s = 0; s < 4; s++) {
    int slot = s * 256 + tid;        // wave-contiguous: slot = s*256 + wave*64 + lane
    int row = slot >> 3;             // 0..127
    int ch = slot & 7;               // 0..7
    int sch = ch ^ (row & 7);        // swizzled source chunk
    gA[s] = A + (long)(bm0 + row) * KDIM + sch * 8;
    gB[s] = B + (long)(bn0 + row) * KDIM + sch * 8;
    offS[s] = slot * 8;              // shorts; = row*64 + ch*8
  }

  // ---- fragment read offsets (shorts), chunk-XOR swizzled
  int aoff[2][4], boff[2][4];
#pragma unroll
  for (int kk = 0; kk < 2; kk++) {
#pragma unroll
    for (int i = 0; i < 4; i++) {
      int ar = wm * 64 + i * 16 + r16;
      aoff[kk][i] = ar * BK + (((kk * 4 + quad) ^ (ar & 7)) * 8);
      int br = wn * 64 + i * 16 + r16;
      boff[kk][i] = br * BK + (((kk * 4 + quad) ^ (br & 7)) * 8);
    }
  }

  f32x4 acc[4][4] = {};

  unsigned short *sa0 = As[0], *sa1 = As[1];
  unsigned short *sb0 = Bs[0], *sb1 = Bs[1];

#define STAGE(SA, SB, T)                                                            \
  do {                                                                              \
    _Pragma("unroll") for (int s = 0; s < 4; s++) {                                 \
      __builtin_amdgcn_global_load_lds(                                             \
          (const __attribute__((address_space(1))) void*)(gA[s] + (long)(T) * BK),  \
          (__attribute__((address_space(3))) void*)((SA) + offS[s]), 16, 0, 0);     \
      __builtin_amdgcn_global_load_lds(                                             \
          (const __attribute__((address_space(1))) void*)(gB[s] + (long)(T) * BK),  \
          (__attribute__((address_space(3))) void*)((SB) + offS[s]), 16, 0, 0);     \
    }                                                                               \
  } while (0)

#define COMPUTE(SA, SB)                                                             \
  do {                                                                              \
    _Pragma("unroll") for (int kk = 0; kk < 2; kk++) {                              \
      bf16x8 af[4], bfr[4];                                                         \
      _Pragma("unroll") for (int i = 0; i < 4; i++)                                 \
        af[i] = *(const bf16x8*)((SA) + aoff[kk][i]);                               \
      _Pragma("unroll") for (int j = 0; j < 4; j++)                                 \
        bfr[j] = *(const bf16x8*)((SB) + boff[kk][j]);                              \
      _Pragma("unroll") for (int i = 0; i < 4; i++)                                 \
        _Pragma("unroll") for (int j = 0; j < 4; j++)                               \
          acc[i][j] =                                                               \
              __builtin_amdgcn_mfma_f32_16x16x32_bf16(af[i], bfr[j], acc[i][j],     \
                                                      0, 0, 0);                     \
    }                                                                               \
  } while (0)

  // prologue: 2 tiles in flight (16 outstanding global_load_lds per wave);
  // vmcnt(8) completes tile 0, leaves tile 1's 8 loads in flight.
  STAGE(sa0, sb0, 0);
  STAGE(sa1, sb1, 1);
  asm volatile("s_waitcnt vmcnt(8)" ::: "memory");
  __builtin_amdgcn_s_barrier();
  __builtin_amdgcn_sched_barrier(0);

#pragma unroll 1
  for (int t = 0; t < NT; t++) {
    COMPUTE(sa0, sb0);
    if (t == NT - 1) break;
    // B1: all waves done reading buf cur -> safe to overwrite with tile t+2.
    asm volatile("s_waitcnt lgkmcnt(0)" ::: "memory");
    __builtin_amdgcn_s_barrier();
    __builtin_amdgcn_sched_barrier(0);
    if (t + 2 < NT) {
      STAGE(sa0, sb0, t + 2);                          // 16 in flight again
      asm volatile("s_waitcnt vmcnt(8)" ::: "memory"); // tile t+1 landed
    } else {
      asm volatile("s_waitcnt vmcnt(0)" ::: "memory"); // last tile landed
    }
    // B2: tile t+1 visible to all waves.
    __builtin_amdgcn_s_barrier();
    __builtin_amdgcn_sched_barrier(0);
    unsigned short* tmp;
    tmp = sa0; sa0 = sa1; sa1 = tmp;
    tmp = sb0; sb0 = sb1; sb1 = tmp;
  }

#undef STAGE
#undef COMPUTE

  // Epilogue: C/D layout col = lane&15, row = quad*4 + reg
#pragma unroll
  for (int i = 0; i < 4; i++) {
#pragma unroll
    for (int j = 0; j < 4; j++) {
      const int row = bm0 + wm * 64 + i * 16 + quad * 4;
      const int col = bn0 + wn * 64 + j * 16 + r16;
#pragma unroll
      for (int r = 0; r < 4; r++)
        C[(long)(row + r) * N + col] = acc[i][j][r];
    }
  }
}

extern "C" void kernel_launch(void* const* d_in, const int* in_sizes, int n_in,
                              void* d_out, int out_size, void* d_ws, size_t ws_size,
                              hipStream_t stream) {
  const float* x = (const float*)d_in[0];   // [M, K] fp32
  const float* w = (const float*)d_in[1];   // [N, K] fp32
  float* out = (float*)d_out;               // [M, N] fp32

  const int MK = in_sizes[0];
  const int NK = in_sizes[1];
  const int M = MK / KDIM;
  const int N = NK / KDIM;

  unsigned short* xq = (unsigned short*)d_ws;        // [M, K] bf16
  unsigned short* wq = xq + (size_t)MK;              // [N, K] bf16

  const int nsub_x = MK / 32;
  const int nsub_total = nsub_x + NK / 32;
  nvfp4_quant_dq2<<<dim3((nsub_total * 8 + 255) / 256), dim3(256), 0, stream>>>(
      x, xq, nsub_x, w, wq, nsub_total);

  dim3 grid((N / BN) * (M / BM));
  gemm_bf16_bt<<<grid, dim3(256), 0, stream>>>(xq, wq, out, M, N);
}

// Round 4
// 166.162 us; speedup vs baseline: 1.0824x; 1.0824x over previous
//
#include <hip/hip_runtime.h>
#include <hip/hip_bf16.h>
#include <stdint.h>

#define KDIM 4096
#define BM 64
#define BN 128
#define BK 64
#define NT (KDIM / BK)   // 64 K-steps

typedef __attribute__((ext_vector_type(8))) short bf16x8;
typedef __attribute__((ext_vector_type(4))) float f32x4;

__device__ inline unsigned short f2bf_bits(float f) {
  union { __hip_bfloat16 h; unsigned short u; } cv;
  cv.h = __float2bfloat16(f);
  return cv.u;
}

// Replicates: scaled = t / bm * 6; q = sign * nearest_palette(|scaled|) (ties -> lower);
// dq = q * (bm/6), rounded to bf16. Division kept exact (fp32 div) so palette
// boundary decisions bit-match the reference.
__device__ inline unsigned short qdq(float t, float bm, float scale) {
  float s = t / bm;
  s = s * 6.0f;
  float a = fabsf(s);
  float v;
  if (a <= 0.25f)      v = 0.0f;
  else if (a <= 0.75f) v = 0.5f;
  else if (a <= 1.25f) v = 1.0f;
  else if (a <= 1.75f) v = 1.5f;
  else if (a <= 2.5f)  v = 2.0f;
  else if (a <= 3.5f)  v = 3.0f;
  else if (a <= 5.0f)  v = 4.0f;
  else                 v = 6.0f;
  float q = copysignf(v, s);
  return f2bf_bits(q * scale);
}

// Fused quant+dequant for both tensors. One 8-lane subgroup = one 32-elem block.
__global__ void nvfp4_quant_dq2(const float* __restrict__ x, unsigned short* __restrict__ xq,
                                int nsub_x,
                                const float* __restrict__ w, unsigned short* __restrict__ wq,
                                int nsub_total) {
  int gid = blockIdx.x * blockDim.x + threadIdx.x;
  int sub = gid >> 3;
  if (sub >= nsub_total) return;
  const float* in;
  unsigned short* out;
  if (sub < nsub_x) { in = x; out = xq; }
  else { in = w; out = wq; sub -= nsub_x; }
  int l8 = gid & 7;
  long base = (long)sub * 32 + (long)l8 * 4;
  const float4 v = *(const float4*)(in + base);
  float amax = fmaxf(fmaxf(fabsf(v.x), fabsf(v.y)), fmaxf(fabsf(v.z), fabsf(v.w)));
  amax = fmaxf(amax, __shfl_xor(amax, 1));
  amax = fmaxf(amax, __shfl_xor(amax, 2));
  amax = fmaxf(amax, __shfl_xor(amax, 4));
  float bm = fmaxf(amax, 1e-12f);   // jnp.clip(max, 1e-12)
  float scale = bm / 6.0f;
  ushort4 o;
  o.x = qdq(v.x, bm, scale);
  o.y = qdq(v.y, bm, scale);
  o.z = qdq(v.z, bm, scale);
  o.w = qdq(v.w, bm, scale);
  *(ushort4*)(out + base) = o;
}

// C[M,N] = A[M,K](bf16) * B[N,K]^T(bf16).
// 64x128 tile, BK=64, 4 waves (2x2), each wave 32x64 via 2x4 grid of 16x16x32 MFMA.
// Grid = 16x32 = 512 blocks = 2 independent blocks/CU (TLP restored — R3 showed
// grid=256 caps occupancy at 1 block/CU regardless of LDS). Double-buffered 48 KB
// LDS; counted s_waitcnt vmcnt(6); raw s_barriers (no forced vmcnt(0) drain).
// Chunk-XOR swizzle on GLOBAL source + ds_read addr (bank conflicts = 0, R1-proven).
__global__ __launch_bounds__(256, 2) void gemm_bf16_bt(
    const unsigned short* __restrict__ A,  // [M, K]
    const unsigned short* __restrict__ B,  // [N, K]
    float* __restrict__ C, int M, int N) {
  __shared__ unsigned short As[2][BM * BK];   // 2 x 8 KB
  __shared__ unsigned short Bs[2][BN * BK];   // 2 x 16 KB  (48 KB total)

  const int tid = threadIdx.x;
  const int wave = tid >> 6;
  const int lane = tid & 63;
  const int wm = wave >> 1;       // 0..1  (32-row half)
  const int wn = wave & 1;        // 0..1  (64-col half)
  const int quad = lane >> 4;     // 0..3
  const int r16 = lane & 15;      // 0..15

  const int nbx = N / BN;
  const int nby = M / BM;
  int bx, by;
  {
    int bid = blockIdx.x;
    if (nbx == 32 && nby == 16) {
      // XCD-chunked swizzle (512 = 8 XCD x 64, bijective): XCD x owns bx in
      // [4x, 4x+4) — its B-panels are XCD-private in L2 (read 16x, fetched once).
      // Consecutive c share by -> A-panel (512 KB) L2-resident while B streams.
      int xcd = bid & 7;
      int c = bid >> 3;            // 0..63
      bx = xcd * 4 + (c & 3);
      by = c >> 2;                 // 0..15
    } else {
      bx = bid % nbx;
      by = bid / nbx;
    }
  }
  const int bm0 = by * BM;
  const int bn0 = bx * BN;

  // ---- staging map: rows x 8 chunks of 16B. A: 512 slots (2/thread),
  // B: 1024 slots (4/thread). LDS slot (row, ch) receives GLOBAL chunk
  // (ch ^ (row&7)) [inverse-swizzled source, linear LDS dest].
  const unsigned short* gA[2];
  const unsigned short* gB[4];
  int offA[2], offB[4];
#pragma unroll
  for (int s = 0; s < 2; s++) {
    int slot = s * 256 + tid;        // 0..511
    int row = slot >> 3;             // 0..63
    int ch = slot & 7;
    int sch = ch ^ (row & 7);
    gA[s] = A + (long)(bm0 + row) * KDIM + sch * 8;
    offA[s] = slot * 8;
  }
#pragma unroll
  for (int s = 0; s < 4; s++) {
    int slot = s * 256 + tid;        // 0..1023
    int row = slot >> 3;             // 0..127
    int ch = slot & 7;
    int sch = ch ^ (row & 7);
    gB[s] = B + (long)(bn0 + row) * KDIM + sch * 8;
    offB[s] = slot * 8;
  }

  // ---- fragment read offsets (shorts), chunk-XOR swizzled
  int aoff[2][2], boff[2][4];
#pragma unroll
  for (int kk = 0; kk < 2; kk++) {
#pragma unroll
    for (int i = 0; i < 2; i++) {
      int ar = wm * 32 + i * 16 + r16;
      aoff[kk][i] = ar * BK + (((kk * 4 + quad) ^ (ar & 7)) * 8);
    }
#pragma unroll
    for (int j = 0; j < 4; j++) {
      int br = wn * 64 + j * 16 + r16;
      boff[kk][j] = br * BK + (((kk * 4 + quad) ^ (br & 7)) * 8);
    }
  }

  f32x4 acc[2][4] = {};

  unsigned short *sa0 = As[0], *sa1 = As[1];
  unsigned short *sb0 = Bs[0], *sb1 = Bs[1];

#define STAGE(SA, SB, T)                                                            \
  do {                                                                              \
    _Pragma("unroll") for (int s = 0; s < 2; s++)                                   \
      __builtin_amdgcn_global_load_lds(                                             \
          (const __attribute__((address_space(1))) void*)(gA[s] + (long)(T) * BK),  \
          (__attribute__((address_space(3))) void*)((SA) + offA[s]), 16, 0, 0);     \
    _Pragma("unroll") for (int s = 0; s < 4; s++)                                   \
      __builtin_amdgcn_global_load_lds(                                             \
          (const __attribute__((address_space(1))) void*)(gB[s] + (long)(T) * BK),  \
          (__attribute__((address_space(3))) void*)((SB) + offB[s]), 16, 0, 0);     \
  } while (0)

#define COMPUTE(SA, SB)                                                             \
  do {                                                                              \
    _Pragma("unroll") for (int kk = 0; kk < 2; kk++) {                              \
      bf16x8 af[2], bfr[4];                                                         \
      _Pragma("unroll") for (int i = 0; i < 2; i++)                                 \
        af[i] = *(const bf16x8*)((SA) + aoff[kk][i]);                               \
      _Pragma("unroll") for (int j = 0; j < 4; j++)                                 \
        bfr[j] = *(const bf16x8*)((SB) + boff[kk][j]);                              \
      _Pragma("unroll") for (int i = 0; i < 2; i++)                                 \
        _Pragma("unroll") for (int j = 0; j < 4; j++)                               \
          acc[i][j] =                                                               \
              __builtin_amdgcn_mfma_f32_16x16x32_bf16(af[i], bfr[j], acc[i][j],     \
                                                      0, 0, 0);                     \
    }                                                                               \
  } while (0)

  // prologue: 2 tiles in flight (12 outstanding global_load_lds per thread);
  // vmcnt(6) completes tile 0, leaves tile 1's 6 loads in flight.
  STAGE(sa0, sb0, 0);
  STAGE(sa1, sb1, 1);
  asm volatile("s_waitcnt vmcnt(6)" ::: "memory");
  __builtin_amdgcn_s_barrier();
  __builtin_amdgcn_sched_barrier(0);

#pragma unroll 1
  for (int t = 0; t < NT; t++) {
    COMPUTE(sa0, sb0);
    if (t == NT - 1) break;
    // B1: all waves done reading buf cur -> safe to overwrite with tile t+2.
    asm volatile("s_waitcnt lgkmcnt(0)" ::: "memory");
    __builtin_amdgcn_s_barrier();
    __builtin_amdgcn_sched_barrier(0);
    if (t + 2 < NT) {
      STAGE(sa0, sb0, t + 2);                          // 12 in flight again
      asm volatile("s_waitcnt vmcnt(6)" ::: "memory"); // tile t+1 landed
    } else {
      asm volatile("s_waitcnt vmcnt(0)" ::: "memory"); // last tile landed
    }
    // B2: tile t+1 visible to all waves.
    __builtin_amdgcn_s_barrier();
    __builtin_amdgcn_sched_barrier(0);
    unsigned short* tmp;
    tmp = sa0; sa0 = sa1; sa1 = tmp;
    tmp = sb0; sb0 = sb1; sb1 = tmp;
  }

#undef STAGE
#undef COMPUTE

  // Epilogue: C/D layout col = lane&15, row = quad*4 + reg
#pragma unroll
  for (int i = 0; i < 2; i++) {
#pragma unroll
    for (int j = 0; j < 4; j++) {
      const int row = bm0 + wm * 32 + i * 16 + quad * 4;
      const int col = bn0 + wn * 64 + j * 16 + r16;
#pragma unroll
      for (int r = 0; r < 4; r++)
        C[(long)(row + r) * N + col] = acc[i][j][r];
    }
  }
}

extern "C" void kernel_launch(void* const* d_in, const int* in_sizes, int n_in,
                              void* d_out, int out_size, void* d_ws, size_t ws_size,
                              hipStream_t stream) {
  const float* x = (const float*)d_in[0];   // [M, K] fp32
  const float* w = (const float*)d_in[1];   // [N, K] fp32
  float* out = (float*)d_out;               // [M, N] fp32

  const int MK = in_sizes[0];
  const int NK = in_sizes[1];
  const int M = MK / KDIM;
  const int N = NK / KDIM;

  unsigned short* xq = (unsigned short*)d_ws;        // [M, K] bf16
  unsigned short* wq = xq + (size_t)MK;              // [N, K] bf16

  const int nsub_x = MK / 32;
  const int nsub_total = nsub_x + NK / 32;
  nvfp4_quant_dq2<<<dim3((nsub_total * 8 + 255) / 256), dim3(256), 0, stream>>>(
      x, xq, nsub_x, w, wq, nsub_total);

  dim3 grid((N / BN) * (M / BM));
  gemm_bf16_bt<<<grid, dim3(256), 0, stream>>>(xq, wq, out, M, N);
}